// Round 3
// baseline (128.637 us; speedup 1.0000x reference)
//
#include <hip/hip_runtime.h>

#define S 512
#define H 128
#define NROW 4096   // B*S
#define TI 8

// ---------------- kernel 0: W1 [128][256] -> w1T [256][128] ----------------
__global__ __launch_bounds__(256) void w1t_kernel(const float* __restrict__ W1,
                                                  float* __restrict__ w1T) {
  __shared__ float t[32][33];
  const int d0 = (blockIdx.x & 7) * 32;   // col tile (d in 0..255)
  const int h0 = (blockIdx.x >> 3) * 32;  // row tile (h in 0..127)
  const int tx = threadIdx.x & 31, ty = threadIdx.x >> 5;  // ty 0..7
  #pragma unroll
  for (int r = 0; r < 4; r++)
    t[ty + r * 8][tx] = W1[(h0 + ty + r * 8) * 256 + d0 + tx];
  __syncthreads();
  #pragma unroll
  for (int r = 0; r < 4; r++)
    w1T[(size_t)(d0 + ty + r * 8) * H + h0 + tx] = t[tx][ty + r * 8];
}

// ---------------- kernel 1: projection ----------------
// qp[row][h]  = sum_d query[row][d]*w1T[d][h] + b1[h]
// kp2[h/16][row][h%16] = sum_d key[row][d]*w1T[128+d][h]
// qw[row] = 0.5*sum_h qp[row][h]*W2[h] + b2;  kw[row] = 0.5*sum_h kp[row][h]*W2[h]
__global__ __launch_bounds__(256) void proj_kernel(
    const float* __restrict__ query, const float* __restrict__ key,
    const float* __restrict__ w1T, const float* __restrict__ b1,
    const float* __restrict__ W2, const float* __restrict__ b2,
    float* __restrict__ qp, float* __restrict__ kp2,
    float* __restrict__ qw, float* __restrict__ kw)
{
  const int bid = blockIdx.x;        // 0..511
  const bool isq = bid < 256;
  const float* __restrict__ src = isq ? query : key;
  const int rbase = (isq ? bid : bid - 256) * 16;
  const int doff = isq ? 0 : 128;
  const int tid = threadIdx.x;
  const int w = __builtin_amdgcn_readfirstlane(tid >> 6);
  const int lane = tid & 63;
  const int r0w = rbase + w * 4;     // this wave's 4 rows

  float acc[4][2];
  float2 bv = make_float2(0.f, 0.f);
  if (isq) bv = *(const float2*)(b1 + 2 * lane);
  #pragma unroll
  for (int r = 0; r < 4; r++) { acc[r][0] = bv.x; acc[r][1] = bv.y; }

  for (int dc = 0; dc < 128; dc += 8) {
    float qs[4][8];                  // wave-uniform -> s_load
    #pragma unroll
    for (int r = 0; r < 4; r++) {
      const float* sp = src + (size_t)(r0w + r) * H + dc;
      #pragma unroll
      for (int u = 0; u < 8; u++) qs[r][u] = sp[u];
    }
    #pragma unroll
    for (int dd = 0; dd < 8; dd++) {
      const float2 wv =
          *(const float2*)(w1T + (size_t)(doff + dc + dd) * H + 2 * lane);
      #pragma unroll
      for (int r = 0; r < 4; r++) {
        acc[r][0] = __builtin_fmaf(qs[r][dd], wv.x, acc[r][0]);
        acc[r][1] = __builtin_fmaf(qs[r][dd], wv.y, acc[r][1]);
      }
    }
  }

  // qw / kw: wave butterfly over h (lane owns h = 2*lane, 2*lane+1)
  const float2 w2p = *(const float2*)(W2 + 2 * lane);
  const float b2v = b2[0];
  #pragma unroll
  for (int r = 0; r < 4; r++) {
    float t = acc[r][0] * w2p.x + acc[r][1] * w2p.y;
    #pragma unroll
    for (int m = 1; m <= 32; m <<= 1) t += __shfl_xor(t, m, 64);
    if (lane == 0) {
      if (isq) qw[r0w + r] = 0.5f * t + b2v;
      else     kw[r0w + r] = 0.5f * t;
    }
  }

  if (isq) {
    #pragma unroll
    for (int r = 0; r < 4; r++)
      *(float2*)(qp + (size_t)(r0w + r) * H + 2 * lane) =
          make_float2(acc[r][0], acc[r][1]);
  } else {
    // kp2[hblk][row][u]: hblk = (2*lane)/16 = lane>>3, u = (2*lane)%16
    #pragma unroll
    for (int r = 0; r < 4; r++)
      *(float2*)(kp2 + ((size_t)(lane >> 3) * NROW + (r0w + r)) * 16 +
                 (lane & 7) * 2) = make_float2(acc[r][0], acc[r][1]);
  }
}

// ---------------- kernel 2: fused scores + exp + AV + output ----------------
// grid: 512 i-tiles; 512 threads = 8 waves; wave w owns j-block w*64..w*64+63.
__global__ __launch_bounds__(512) void attn_kernel(
    const float* __restrict__ qp, const float* __restrict__ kp2,
    const float* __restrict__ qw, const float* __restrict__ kw,
    const float* __restrict__ value, const int* __restrict__ q_mask,
    const int* __restrict__ k_mask, const float* __restrict__ W2,
    float* __restrict__ out)
{
  __shared__ float aT[8][64][8];      // a, per wave [j][i]
  __shared__ float numw[8][TI][132];  // per-wave num partials
  __shared__ float denw[8][TI];

  const int it = blockIdx.x;          // 0..511
  const int r0 = it * TI;
  const int b  = r0 >> 9;
  const int tid = threadIdx.x;
  const int w = __builtin_amdgcn_readfirstlane(tid >> 6);
  const int lane = tid & 63;
  const int jg = (b << 9) + (w << 6) + lane;   // global key row
  const int km = k_mask[jg];
  const float kwj = kw[jg];

  // ---- phase 1: s[i] = sum_h |q+k| * W2  (then *0.5 at the end) ----
  float s[TI];
  #pragma unroll
  for (int i = 0; i < TI; i++) s[i] = 0.f;

  #pragma unroll
  for (int hb = 0; hb < 8; hb++) {
    const float* __restrict__ kptr = kp2 + (((size_t)hb * NROW + jg) << 4);
    const float4 k0 = ((const float4*)kptr)[0];
    const float4 k1 = ((const float4*)kptr)[1];
    const float4 k2 = ((const float4*)kptr)[2];
    const float4 k3 = ((const float4*)kptr)[3];
    const float4* __restrict__ w2c = (const float4*)(W2 + hb * 16);  // uniform
    const float4 w0 = w2c[0], w1 = w2c[1], w2_ = w2c[2], w3 = w2c[3];
    #pragma unroll
    for (int i = 0; i < TI; i++) {
      const float4* __restrict__ qptr =
          (const float4*)(qp + (size_t)(r0 + i) * H + hb * 16);  // uniform
      const float4 q0 = qptr[0], q1 = qptr[1], q2 = qptr[2], q3 = qptr[3];
      float t, si = s[i];
      t = q0.x + k0.x; si = __builtin_fmaf(fabsf(t), w0.x, si);
      t = q0.y + k0.y; si = __builtin_fmaf(fabsf(t), w0.y, si);
      t = q0.z + k0.z; si = __builtin_fmaf(fabsf(t), w0.z, si);
      t = q0.w + k0.w; si = __builtin_fmaf(fabsf(t), w0.w, si);
      t = q1.x + k1.x; si = __builtin_fmaf(fabsf(t), w1.x, si);
      t = q1.y + k1.y; si = __builtin_fmaf(fabsf(t), w1.y, si);
      t = q1.z + k1.z; si = __builtin_fmaf(fabsf(t), w1.z, si);
      t = q1.w + k1.w; si = __builtin_fmaf(fabsf(t), w1.w, si);
      t = q2.x + k2.x; si = __builtin_fmaf(fabsf(t), w2_.x, si);
      t = q2.y + k2.y; si = __builtin_fmaf(fabsf(t), w2_.y, si);
      t = q2.z + k2.z; si = __builtin_fmaf(fabsf(t), w2_.z, si);
      t = q2.w + k2.w; si = __builtin_fmaf(fabsf(t), w2_.w, si);
      t = q3.x + k3.x; si = __builtin_fmaf(fabsf(t), w3.x, si);
      t = q3.y + k3.y; si = __builtin_fmaf(fabsf(t), w3.y, si);
      t = q3.z + k3.z; si = __builtin_fmaf(fabsf(t), w3.z, si);
      t = q3.w + k3.w; si = __builtin_fmaf(fabsf(t), w3.w, si);
      s[i] = si;
    }
  }

  // ---- mask + exp ----
  float a[TI];
  #pragma unroll
  for (int i = 0; i < TI; i++) {
    const float qws = qw[r0 + i];     // uniform (b2 folded in)
    const int qm = q_mask[r0 + i];    // uniform
    a[i] = (km > 0 && qm > 0) ? __expf(__builtin_fmaf(0.5f, s[i], qws + kwj))
                              : 0.f;
  }
  #pragma unroll
  for (int i = 0; i < TI; i += 2)
    *(float2*)&aT[w][lane][i] = make_float2(a[i], a[i + 1]);
  __syncthreads();

  // ---- phase 2: num[i][h] += a[i][j]*v[j][h]; den folded in ----
  const int lj = lane >> 5, lh = lane & 31;
  float nr[TI][4];
  float dden[TI];
  #pragma unroll
  for (int i = 0; i < TI; i++) {
    nr[i][0] = 0.f; nr[i][1] = 0.f; nr[i][2] = 0.f; nr[i][3] = 0.f;
    dden[i] = 0.f;
  }
  const float* __restrict__ vbase =
      value + ((size_t)b * S + (w << 6)) * H;

  for (int js = 0; js < 32; js++) {
    const int j = js * 2 + lj;
    const float4 vv = *(const float4*)(vbase + (size_t)j * H + lh * 4);
    const float4 a0 = *(const float4*)&aT[w][j][0];
    const float4 a1 = *(const float4*)&aT[w][j][4];
    const float av[8] = {a0.x, a0.y, a0.z, a0.w, a1.x, a1.y, a1.z, a1.w};
    #pragma unroll
    for (int i = 0; i < TI; i++) {
      nr[i][0] = __builtin_fmaf(av[i], vv.x, nr[i][0]);
      nr[i][1] = __builtin_fmaf(av[i], vv.y, nr[i][1]);
      nr[i][2] = __builtin_fmaf(av[i], vv.z, nr[i][2]);
      nr[i][3] = __builtin_fmaf(av[i], vv.w, nr[i][3]);
      dden[i] += av[i];
    }
  }
  #pragma unroll
  for (int i = 0; i < TI; i++) {
    #pragma unroll
    for (int k = 0; k < 4; k++) nr[i][k] += __shfl_xor(nr[i][k], 32, 64);
    dden[i] += __shfl_xor(dden[i], 32, 64);
  }
  if (lj == 0) {
    #pragma unroll
    for (int i = 0; i < TI; i++)
      *(float4*)&numw[w][i][lh * 4] =
          make_float4(nr[i][0], nr[i][1], nr[i][2], nr[i][3]);
    if (lane == 0) {
      #pragma unroll
      for (int i = 0; i < TI; i++) denw[w][i] = dden[i];
    }
  }
  __syncthreads();

  // ---- final: sum 8 wave-partials, divide, store (row i = w) ----
  {
    const int i = w;
    float2 acc = make_float2(0.f, 0.f);
    float den = 0.f;
    #pragma unroll
    for (int ww = 0; ww < 8; ww++) {
      const float2 p = *(const float2*)&numw[ww][i][lane * 2];
      acc.x += p.x; acc.y += p.y;
      den += denw[ww][i];
    }
    const float inv = 1.f / fmaxf(den, 2e-15f);
    *(float2*)(out + (size_t)(r0 + i) * H + lane * 2) =
        make_float2(acc.x * inv, acc.y * inv);
  }
}

extern "C" void kernel_launch(void* const* d_in, const int* in_sizes, int n_in,
                              void* d_out, int out_size, void* d_ws, size_t ws_size,
                              hipStream_t stream)
{
  (void)in_sizes; (void)n_in; (void)out_size; (void)ws_size;
  const float* query  = (const float*)d_in[0];
  const float* key    = (const float*)d_in[1];
  const float* value  = (const float*)d_in[2];
  const int*   q_mask = (const int*)d_in[3];
  const int*   k_mask = (const int*)d_in[4];
  const float* W1     = (const float*)d_in[5];
  const float* b1     = (const float*)d_in[6];
  const float* W2     = (const float*)d_in[7];
  const float* b2     = (const float*)d_in[8];
  float* out = (float*)d_out;

  float* ws   = (float*)d_ws;
  float* w1T  = ws;                                  // [256][128]
  float* qp   = w1T + 256 * H;                       // [4096][128]
  float* kp2  = qp + (size_t)NROW * H;               // [8][4096][16]
  float* qw   = kp2 + (size_t)NROW * H;              // [4096]
  float* kw   = qw + NROW;                           // [4096]

  w1t_kernel<<<32, 256, 0, stream>>>(W1, w1T);
  proj_kernel<<<512, 256, 0, stream>>>(query, key, w1T, b1, W2, b2,
                                       qp, kp2, qw, kw);
  attn_kernel<<<512, 512, 0, stream>>>(qp, kp2, qw, kw, value, q_mask,
                                       k_mask, W2, out);
}

// Round 4
// 124.980 us; speedup vs baseline: 1.0293x; 1.0293x over previous
//
#include <hip/hip_runtime.h>

#define S 512
#define H 128
#define NROW 4096   // B*S
#define TI 8

// ---------------- kernel 0: W1 [128][256] -> w1T [256][128] ----------------
__global__ __launch_bounds__(256) void w1t_kernel(const float* __restrict__ W1,
                                                  float* __restrict__ w1T) {
  __shared__ float t[32][33];
  const int d0 = (blockIdx.x & 7) * 32;   // col tile (d in 0..255)
  const int h0 = (blockIdx.x >> 3) * 32;  // row tile (h in 0..127)
  const int tx = threadIdx.x & 31, ty = threadIdx.x >> 5;  // ty 0..7
  #pragma unroll
  for (int r = 0; r < 4; r++)
    t[ty + r * 8][tx] = W1[(h0 + ty + r * 8) * 256 + d0 + tx];
  __syncthreads();
  #pragma unroll
  for (int r = 0; r < 4; r++)
    w1T[(size_t)(d0 + ty + r * 8) * H + h0 + tx] = t[tx][ty + r * 8];
}

// ---------------- kernel 1: projection ----------------
// qp[row][h]  = sum_d query[row][d]*w1T[d][h] + b1[h]
// kp2[h/16][row][h%16] = sum_d key[row][d]*w1T[128+d][h]
// qw[row] = 0.5*sum_h qp[row][h]*W2[h] + b2;  kw[row] = 0.5*sum_h kp[row][h]*W2[h]
__global__ __launch_bounds__(256) void proj_kernel(
    const float* __restrict__ query, const float* __restrict__ key,
    const float* __restrict__ w1T, const float* __restrict__ b1,
    const float* __restrict__ W2, const float* __restrict__ b2,
    float* __restrict__ qp, float* __restrict__ kp2,
    float* __restrict__ qw, float* __restrict__ kw)
{
  const int bid = blockIdx.x;        // 0..511
  const bool isq = bid < 256;
  const float* __restrict__ src = isq ? query : key;
  const int rbase = (isq ? bid : bid - 256) * 16;
  const int doff = isq ? 0 : 128;
  const int tid = threadIdx.x;
  const int w = __builtin_amdgcn_readfirstlane(tid >> 6);
  const int lane = tid & 63;
  const int r0w = rbase + w * 4;     // this wave's 4 rows

  float acc[4][2];
  float2 bv = make_float2(0.f, 0.f);
  if (isq) bv = *(const float2*)(b1 + 2 * lane);
  #pragma unroll
  for (int r = 0; r < 4; r++) { acc[r][0] = bv.x; acc[r][1] = bv.y; }

  // 16-d chunks: 4x s_load_dwordx16 (src, uniform) + 16 coalesced float2 (w1T)
  // feeding 128 FMAs per chunk.
  #pragma unroll 1
  for (int dc = 0; dc < 128; dc += 16) {
    float qs[4][16];                 // wave-uniform -> SGPR batch
    #pragma unroll
    for (int r = 0; r < 4; r++) {
      const float* sp = src + (size_t)(r0w + r) * H + dc;
      #pragma unroll
      for (int u = 0; u < 16; u++) qs[r][u] = sp[u];
    }
    float2 wv[16];
    #pragma unroll
    for (int dd = 0; dd < 16; dd++)
      wv[dd] = *(const float2*)(w1T + (size_t)(doff + dc + dd) * H + 2 * lane);
    #pragma unroll
    for (int dd = 0; dd < 16; dd++) {
      #pragma unroll
      for (int r = 0; r < 4; r++) {
        acc[r][0] = __builtin_fmaf(qs[r][dd], wv[dd].x, acc[r][0]);
        acc[r][1] = __builtin_fmaf(qs[r][dd], wv[dd].y, acc[r][1]);
      }
    }
  }

  // qw / kw: wave butterfly over h (lane owns h = 2*lane, 2*lane+1)
  const float2 w2p = *(const float2*)(W2 + 2 * lane);
  const float b2v = b2[0];
  #pragma unroll
  for (int r = 0; r < 4; r++) {
    float t = acc[r][0] * w2p.x + acc[r][1] * w2p.y;
    #pragma unroll
    for (int m = 1; m <= 32; m <<= 1) t += __shfl_xor(t, m, 64);
    if (lane == 0) {
      if (isq) qw[r0w + r] = 0.5f * t + b2v;
      else     kw[r0w + r] = 0.5f * t;
    }
  }

  if (isq) {
    #pragma unroll
    for (int r = 0; r < 4; r++)
      *(float2*)(qp + (size_t)(r0w + r) * H + 2 * lane) =
          make_float2(acc[r][0], acc[r][1]);
  } else {
    // kp2[hblk][row][u]: hblk = (2*lane)/16 = lane>>3, u = (2*lane)%16
    #pragma unroll
    for (int r = 0; r < 4; r++)
      *(float2*)(kp2 + ((size_t)(lane >> 3) * NROW + (r0w + r)) * 16 +
                 (lane & 7) * 2) = make_float2(acc[r][0], acc[r][1]);
  }
}

// ---------------- kernel 2: fused scores + exp + AV + output ----------------
// grid: 512 i-tiles; 512 threads = 8 waves; wave w owns j-block w*64..w*64+63.
// Phase 1: k,W2 VGPR-resident per 32-h pass; q streamed as 64-float SGPR
// batches (2 i-rows) feeding 128 dependent-free VALU each.
__global__ __launch_bounds__(512, 4) void attn_kernel(
    const float* __restrict__ qp, const float* __restrict__ kp2,
    const float* __restrict__ qw, const float* __restrict__ kw,
    const float* __restrict__ value, const int* __restrict__ q_mask,
    const int* __restrict__ k_mask, const float* __restrict__ W2,
    float* __restrict__ out)
{
  __shared__ float aT[8][64][8];      // a, per wave [j][i]
  __shared__ float numw[8][TI][132];  // per-wave num partials
  __shared__ float denw[8][TI];

  const int it = blockIdx.x;          // 0..511
  const int r0 = it * TI;
  const int b  = r0 >> 9;
  const int tid = threadIdx.x;
  const int w = __builtin_amdgcn_readfirstlane(tid >> 6);
  const int lane = tid & 63;
  const int jg = (b << 9) + (w << 6) + lane;   // global key row
  const int km = k_mask[jg];
  const float kwj = kw[jg];

  // ---- phase 1: s[i] = sum_h |q+k| * W2  (x0.5 folded at the end) ----
  float s[TI];
  #pragma unroll
  for (int i = 0; i < TI; i++) s[i] = 0.f;

  #pragma unroll 1
  for (int p = 0; p < 4; p++) {       // 32-h window [32p, 32p+32)
    // k-resident: 8 dwordx4 (two 16-h blocks of kp2)
    float kr[32];
    {
      const float* __restrict__ k0 = kp2 + (((size_t)(2 * p) * NROW + jg) << 4);
      const float* __restrict__ k1 = kp2 + (((size_t)(2 * p + 1) * NROW + jg) << 4);
      #pragma unroll
      for (int u = 0; u < 4; u++) {
        *(float4*)&kr[u * 4]      = ((const float4*)k0)[u];
        *(float4*)&kr[16 + u * 4] = ((const float4*)k1)[u];
      }
    }
    // W2-resident (broadcast loads)
    float w2r[32];
    #pragma unroll
    for (int u = 0; u < 8; u++)
      *(float4*)&w2r[u * 4] = ((const float4*)(W2 + p * 32))[u];

    #pragma unroll 1
    for (int ip = 0; ip < TI; ip += 2) {
      // q batch: 2 rows x 32 floats, uniform -> s_load_dwordx16 pairs
      float q0[32], q1[32];
      {
        const float* __restrict__ qa = qp + (size_t)(r0 + ip) * H + p * 32;
        #pragma unroll
        for (int u = 0; u < 32; u++) { q0[u] = qa[u]; q1[u] = qa[H + u]; }
      }
      float s0 = s[ip], s1 = s[ip + 1];
      #pragma unroll
      for (int u = 0; u < 32; u++) {
        const float t0 = q0[u] + kr[u];
        const float t1 = q1[u] + kr[u];
        s0 = __builtin_fmaf(fabsf(t0), w2r[u], s0);
        s1 = __builtin_fmaf(fabsf(t1), w2r[u], s1);
      }
      s[ip] = s0; s[ip + 1] = s1;
    }
  }

  // ---- mask + exp ----
  float a[TI];
  #pragma unroll
  for (int i = 0; i < TI; i++) {
    const float qws = qw[r0 + i];     // uniform (b2 folded in)
    const int qm = q_mask[r0 + i];    // uniform
    a[i] = (km > 0 && qm > 0) ? __expf(__builtin_fmaf(0.5f, s[i], qws + kwj))
                              : 0.f;
  }
  #pragma unroll
  for (int i = 0; i < TI; i += 4)
    *(float4*)&aT[w][lane][i] = make_float4(a[i], a[i+1], a[i+2], a[i+3]);
  // no barrier: aT[w] is wave-private (same wave writes then reads)

  // ---- phase 2: num[i][h] += a[i][j]*v[j][h]; den folded in ----
  const int lj = lane >> 5, lh = lane & 31;
  float nr[TI][4];
  float dden[TI];
  #pragma unroll
  for (int i = 0; i < TI; i++) {
    nr[i][0] = 0.f; nr[i][1] = 0.f; nr[i][2] = 0.f; nr[i][3] = 0.f;
    dden[i] = 0.f;
  }
  const float* __restrict__ vbase =
      value + ((size_t)b * S + (w << 6)) * H;

  #pragma unroll 1
  for (int js = 0; js < 32; js++) {
    const int j = js * 2 + lj;
    const float4 vv = *(const float4*)(vbase + (size_t)j * H + lh * 4);
    const float4 a0 = *(const float4*)&aT[w][j][0];
    const float4 a1 = *(const float4*)&aT[w][j][4];
    const float av[8] = {a0.x, a0.y, a0.z, a0.w, a1.x, a1.y, a1.z, a1.w};
    #pragma unroll
    for (int i = 0; i < TI; i++) {
      nr[i][0] = __builtin_fmaf(av[i], vv.x, nr[i][0]);
      nr[i][1] = __builtin_fmaf(av[i], vv.y, nr[i][1]);
      nr[i][2] = __builtin_fmaf(av[i], vv.z, nr[i][2]);
      nr[i][3] = __builtin_fmaf(av[i], vv.w, nr[i][3]);
      dden[i] += av[i];
    }
  }
  #pragma unroll
  for (int i = 0; i < TI; i++) {
    #pragma unroll
    for (int k = 0; k < 4; k++) nr[i][k] += __shfl_xor(nr[i][k], 32, 64);
    dden[i] += __shfl_xor(dden[i], 32, 64);
  }
  if (lj == 0) {
    #pragma unroll
    for (int i = 0; i < TI; i++)
      *(float4*)&numw[w][i][lh * 4] =
          make_float4(nr[i][0], nr[i][1], nr[i][2], nr[i][3]);
    if (lane == 0) {
      #pragma unroll
      for (int i = 0; i < TI; i++) denw[w][i] = dden[i];
    }
  }
  __syncthreads();

  // ---- final: sum 8 wave-partials, divide, store (row i = w) ----
  {
    const int i = w;
    float2 acc = make_float2(0.f, 0.f);
    float den = 0.f;
    #pragma unroll
    for (int ww = 0; ww < 8; ww++) {
      const float2 p = *(const float2*)&numw[ww][i][lane * 2];
      acc.x += p.x; acc.y += p.y;
      den += denw[ww][i];
    }
    const float inv = 1.f / fmaxf(den, 2e-15f);
    *(float2*)(out + (size_t)(r0 + i) * H + lane * 2) =
        make_float2(acc.x * inv, acc.y * inv);
  }
}

extern "C" void kernel_launch(void* const* d_in, const int* in_sizes, int n_in,
                              void* d_out, int out_size, void* d_ws, size_t ws_size,
                              hipStream_t stream)
{
  (void)in_sizes; (void)n_in; (void)out_size; (void)ws_size;
  const float* query  = (const float*)d_in[0];
  const float* key    = (const float*)d_in[1];
  const float* value  = (const float*)d_in[2];
  const int*   q_mask = (const int*)d_in[3];
  const int*   k_mask = (const int*)d_in[4];
  const float* W1     = (const float*)d_in[5];
  const float* b1     = (const float*)d_in[6];
  const float* W2     = (const float*)d_in[7];
  const float* b2     = (const float*)d_in[8];
  float* out = (float*)d_out;

  float* ws   = (float*)d_ws;
  float* w1T  = ws;                                  // [256][128]
  float* qp   = w1T + 256 * H;                       // [4096][128]
  float* kp2  = qp + (size_t)NROW * H;               // [8][4096][16]
  float* qw   = kp2 + (size_t)NROW * H;              // [4096]
  float* kw   = qw + NROW;                           // [4096]

  w1t_kernel<<<32, 256, 0, stream>>>(W1, w1T);
  proj_kernel<<<512, 256, 0, stream>>>(query, key, w1T, b1, W2, b2,
                                       qp, kp2, qw, kw);
  attn_kernel<<<512, 512, 0, stream>>>(qp, kp2, qw, kw, value, q_mask,
                                       k_mask, W2, out);
}